// Round 2
// baseline (457.250 us; speedup 1.0000x reference)
//
#include <hip/hip_runtime.h>
#include <hip/hip_bf16.h>
#include <cstdint>

typedef unsigned short ushortT;
typedef __attribute__((ext_vector_type(8))) short short8;
typedef __attribute__((ext_vector_type(4))) float f32x4;
typedef __attribute__((ext_vector_type(4))) unsigned short us4;

__device__ __forceinline__ ushortT f2bf(float f) {
  union { float f; unsigned u; } v; v.f = f;
  unsigned r = (v.u + 0x7FFFu + ((v.u >> 16) & 1u)) >> 16;
  return (ushortT)r;
}

__device__ __forceinline__ void gl_lds16(const void* g, void* l) {
  __builtin_amdgcn_global_load_lds(
      (__attribute__((address_space(1))) void*)g,
      (__attribute__((address_space(3))) void*)l, 16, 0, 0);
}

// ---------------- 128x128 tile GEMM, C = A @ B^T, bf16 in, BK=32 -------------
template <int EPI>
__global__ __launch_bounds__(256) void gemm128(
    const ushortT* __restrict__ A, const ushortT* __restrict__ B,
    int M, int N, int K,
    float* __restrict__ outF, ushortT* __restrict__ outBF,
    const float* __restrict__ bias,
    const float* __restrict__ addend,
    float* __restrict__ S2, float* __restrict__ S4,
    ushortT* __restrict__ sdT, int ldT)
{
  __shared__ ushortT sA[2][128 * 32];
  __shared__ ushortT sB[2][128 * 32];
  const int tid = threadIdx.x;
  const int w = tid >> 6, l = tid & 63;
  const int wr = w >> 1, wc = w & 1;
  const int m0 = blockIdx.x * 128, n0 = blockIdx.y * 128;
  const int NK = K >> 5;

  f32x4 acc[4][4] = {};

  auto stage = [&](int buf, int kt) {
    const int k0 = kt << 5;
    const size_t colA = (size_t)(k0 + (l & 3) * 8);
    const int rb = w * 16 + (l >> 2);
#pragma unroll
    for (int c = 0; c < 2; ++c) {
      gl_lds16(A + (size_t)(m0 + c * 64 + rb) * (size_t)K + colA,
               &sA[buf][c * 2048 + w * 512]);
      gl_lds16(B + (size_t)(n0 + c * 64 + rb) * (size_t)K + colA,
               &sB[buf][c * 2048 + w * 512]);
    }
  };

  stage(0, 0);
  __syncthreads();

  for (int kt = 0; kt < NK; ++kt) {
    const int buf = kt & 1;
    if (kt + 1 < NK) stage(buf ^ 1, kt + 1);
    const int ro = (l & 15) * 32 + (l >> 4) * 8;
    short8 a[4], b[4];
#pragma unroll
    for (int f = 0; f < 4; ++f) {
      a[f] = *(const short8*)&sA[buf][(wr * 64 + f * 16) * 32 + ro];
      b[f] = *(const short8*)&sB[buf][(wc * 64 + f * 16) * 32 + ro];
    }
#pragma unroll
    for (int fi = 0; fi < 4; ++fi)
#pragma unroll
      for (int fj = 0; fj < 4; ++fj)
        acc[fi][fj] = __builtin_amdgcn_mfma_f32_16x16x32_bf16(
            a[fi], b[fj], acc[fi][fj], 0, 0, 0);
    __syncthreads();
  }

  const int r4 = (l >> 4) * 4, cc = l & 15;

  if constexpr (EPI == 0) {
#pragma unroll
    for (int fi = 0; fi < 4; ++fi)
#pragma unroll
      for (int r = 0; r < 4; ++r) {
        const size_t gm = (size_t)(m0 + wr * 64 + fi * 16 + r4 + r);
#pragma unroll
        for (int fj = 0; fj < 4; ++fj) {
          const int gn = n0 + wc * 64 + fj * 16 + cc;
          outF[gm * (size_t)N + gn] = acc[fi][fj][r] + bias[gn];
        }
      }
  } else if constexpr (EPI == 1) {
#pragma unroll
    for (int fi = 0; fi < 4; ++fi)
#pragma unroll
      for (int r = 0; r < 4; ++r) {
        const size_t gm = (size_t)(m0 + wr * 64 + fi * 16 + r4 + r);
#pragma unroll
        for (int fj = 0; fj < 4; ++fj) {
          const int gn = n0 + wc * 64 + fj * 16 + cc;
          outBF[gm * (size_t)N + gn] = f2bf(acc[fi][fj][r]);
        }
      }
  } else {
    __shared__ ushortT tbuf[128 * 136];
#pragma unroll
    for (int fi = 0; fi < 4; ++fi)
#pragma unroll
      for (int r = 0; r < 4; ++r) {
        const int row = wr * 64 + fi * 16 + r4 + r;
        const size_t gm = (size_t)(m0 + row);
        float rs2 = 0.f, rs4 = 0.f;
#pragma unroll
        for (int fj = 0; fj < 4; ++fj) {
          const int col = wc * 64 + fj * 16 + cc;
          float sd = acc[fi][fj][r] + addend[gm * (size_t)N + n0 + col];
          tbuf[col * 136 + row] = f2bf(sd);
          float s2 = sd * sd;
          rs2 += s2;
          rs4 += s2 * s2;
        }
#pragma unroll
        for (int mk = 1; mk < 16; mk <<= 1) {
          rs2 += __shfl_xor(rs2, mk, 16);
          rs4 += __shfl_xor(rs4, mk, 16);
        }
        if (cc == 0) { atomicAdd(&S2[gm], rs2); atomicAdd(&S4[gm], rs4); }
      }
    __syncthreads();
#pragma unroll
    for (int i = 0; i < 8; ++i) {
      const int er = i * 16 + (tid >> 4);
      const int nc = (tid & 15) * 8;
      short8 v = *(const short8*)&tbuf[er * 136 + nc];
      *(short8*)&sdT[(size_t)(n0 + er) * (size_t)ldT + m0 + nc] = v;
    }
  }
}

// ---------------- 64x64 tile GEMM for M = sdT @ sdT^T, writes grad ----------
__global__ __launch_bounds__(256) void mgemm64(
    const ushortT* __restrict__ T, int Dm, int K,
    float* __restrict__ grad, float invN)
{
  __shared__ ushortT sA[2][64 * 32];
  __shared__ ushortT sB[2][64 * 32];
  const int tid = threadIdx.x, w = tid >> 6, l = tid & 63;
  const int wr = w >> 1, wc = w & 1;
  const int i0 = blockIdx.x * 64, j0 = blockIdx.y * 64;
  const int NK = K >> 5;
  f32x4 acc[2][2] = {};

  auto stage = [&](int buf, int kt) {
    const int k0 = kt << 5;
    const size_t col = (size_t)(k0 + (l & 3) * 8);
    const int rb = w * 16 + (l >> 2);
    gl_lds16(T + (size_t)(i0 + rb) * (size_t)K + col, &sA[buf][w * 512]);
    gl_lds16(T + (size_t)(j0 + rb) * (size_t)K + col, &sB[buf][w * 512]);
  };

  stage(0, 0);
  __syncthreads();

  for (int kt = 0; kt < NK; ++kt) {
    const int buf = kt & 1;
    if (kt + 1 < NK) stage(buf ^ 1, kt + 1);
    const int ro = (l & 15) * 32 + (l >> 4) * 8;
    short8 a[2], b[2];
#pragma unroll
    for (int f = 0; f < 2; ++f) {
      a[f] = *(const short8*)&sA[buf][(wr * 32 + f * 16) * 32 + ro];
      b[f] = *(const short8*)&sB[buf][(wc * 32 + f * 16) * 32 + ro];
    }
#pragma unroll
    for (int fi = 0; fi < 2; ++fi)
#pragma unroll
      for (int fj = 0; fj < 2; ++fj)
        acc[fi][fj] = __builtin_amdgcn_mfma_f32_16x16x32_bf16(
            a[fi], b[fj], acc[fi][fj], 0, 0, 0);
    __syncthreads();
  }

  const int r4 = (l >> 4) * 4, cc = l & 15;
#pragma unroll
  for (int fi = 0; fi < 2; ++fi)
#pragma unroll
    for (int r = 0; r < 4; ++r) {
      const int gi = i0 + wr * 32 + fi * 16 + r4 + r;
#pragma unroll
      for (int fj = 0; fj < 2; ++fj) {
        const int gj = j0 + wc * 32 + fj * 16 + cc;
        grad[(size_t)gi * (size_t)Dm + gj] =
            0.5f * (acc[fi][fj][r] * invN) - (gi == gj ? 0.5f : 0.0f);
      }
    }
}

// ---------------- small utility kernels -------------------------------------
__global__ void zero_f32(float* __restrict__ p, int n) {
  int i = blockIdx.x * blockDim.x + threadIdx.x;
  if (i < n) p[i] = 0.f;
}

__global__ void cvt_f32_bf16(const float* __restrict__ in, ushortT* __restrict__ out,
                             size_t n4) {
  size_t i = (size_t)blockIdx.x * blockDim.x + threadIdx.x;
  const size_t stride = (size_t)gridDim.x * blockDim.x;
  const float4* in4 = (const float4*)in;
  for (; i < n4; i += stride) {
    float4 v = in4[i];
    us4 o = { f2bf(v.x), f2bf(v.y), f2bf(v.z), f2bf(v.w) };
    *(us4*)(out + i * 4) = o;
  }
}

__global__ void transposeQ(const float* __restrict__ q, ushortT* __restrict__ qT) {
  const int g = blockIdx.x * 256 + threadIdx.x;  // 131072 threads
  const int d = g >> 7;
  const int k0 = (g & 127) << 3;
  short8 v;
#pragma unroll
  for (int j = 0; j < 8; ++j) v[j] = (short)f2bf(q[(size_t)(k0 + j) * 1024 + d]);
  *(short8*)(qT + (size_t)d * 1024 + k0) = v;
}

__global__ void make_p(const float* __restrict__ q, ushortT* __restrict__ p) {
  const int g = blockIdx.x * 256 + threadIdx.x;  // 131072 threads
  const size_t base = (size_t)g * 8;
  const int e = (int)(base >> 10);
  const int d0 = (int)(base & 1023);
  short8 v;
#pragma unroll
  for (int j = 0; j < 8; ++j) {
    float f = q[base + j] - ((e == d0 + j) ? 1.0f : 0.0f);
    v[j] = (short)f2bf(f);
  }
  *(short8*)(p + base) = v;
}

__global__ void gather_rows(const float* __restrict__ x, const int* __restrict__ idx,
                            float* __restrict__ self32, ushortT* __restrict__ selbf) {
  const int bid = blockIdx.x;  // 0..8191
  const int b = bid >> 10;
  const int row = idx[bid] & 4095;  // harness passes int32; clamp for safety
  const float4* src = (const float4*)(x + ((size_t)b * 4096 + (size_t)row) * 1024);
  const int t = threadIdx.x;  // 256 threads * 4 floats = 1024
  float4 v = src[t];
  *(float4*)(self32 + (size_t)bid * 1024 + t * 4) = v;
  us4 o = { f2bf(v.x), f2bf(v.y), f2bf(v.z), f2bf(v.w) };
  *(us4*)(selbf + (size_t)bid * 1024 + t * 4) = o;
}

__global__ void loss_final(const float* __restrict__ S2, const float* __restrict__ S4,
                           float* __restrict__ out) {
  __shared__ double red0[256];
  __shared__ double red1[256];
  const int t = threadIdx.x;
  double ca = 0.0, wa = 0.0;
  for (int i = t; i < 8192; i += 256) {
    double s2 = (double)S2[i], s4 = (double)S4[i];
    ca += s2 * s2 - s4;
    wa += s4 - 2.0 * s2 + 1024.0;
  }
  red0[t] = ca; red1[t] = wa;
  __syncthreads();
  for (int s = 128; s > 0; s >>= 1) {
    if (t < s) { red0[t] += red0[t + s]; red1[t] += red1[t + s]; }
    __syncthreads();
  }
  if (t == 0) {
    const double inv = 1.0 / (8192.0 * 1024.0 * 1024.0);
    out[0] = (float)(red0[0] * inv);
    out[1] = (float)(red1[0] * inv);
  }
}

// ---------------- launch -----------------------------------------------------
extern "C" void kernel_launch(void* const* d_in, const int* in_sizes, int n_in,
                              void* d_out, int out_size, void* d_ws, size_t ws_size,
                              hipStream_t stream) {
  (void)in_sizes; (void)n_in; (void)out_size;
  const float* x = (const float*)d_in[0];       // (8,4096,1024) f32
  const float* weight = (const float*)d_in[1];  // (2048,1024) f32
  const float* bias = (const float*)d_in[2];    // (2048,) f32
  const float* decorr = (const float*)d_in[3];  // (1024,1024) f32
  const int* sidx = (const int*)d_in[4];        // (8,1024) int32

  if (ws_size < 146866176ULL) return;  // need ~140 MiB scratch

  char* ws = (char*)d_ws;
  ushortT* xbf     = (ushortT*)(ws);              // 33,554,432 bf16
  ushortT* fusedbf = (ushortT*)(ws + 67108864);   //  2,097,152 bf16
  ushortT* wbf     = (ushortT*)(ws + 71303168);   //  2,097,152 bf16
  ushortT* qT      = (ushortT*)(ws + 75497472);   //  1,048,576 bf16
  ushortT* pbf     = (ushortT*)(ws + 77594624);   //  1,048,576 bf16
  float*   self32  = (float*)  (ws + 79691776);   //  8,388,608 f32
  ushortT* selbf   = (ushortT*)(ws + 113246208);  //  8,388,608 bf16
  ushortT* sdT     = (ushortT*)(ws + 130023424);  //  8,388,608 bf16 (1024 x 8192)
  float*   S2      = (float*)  (ws + 146800640);  //  8192 f32
  float*   S4      = (float*)  (ws + 146833408);  //  8192 f32

  float* y = (float*)d_out;                          // 8*4096*2048
  float* grad = y + 67108864ULL;                     // 1024*1024
  float* losses = grad + 1048576ULL;                 // 2 scalars

  zero_f32<<<dim3(64), dim3(256), 0, stream>>>(S2, 16384);  // S2+S4 contiguous
  cvt_f32_bf16<<<dim3(2048), dim3(256), 0, stream>>>(x, xbf, 8388608);
  cvt_f32_bf16<<<dim3(512), dim3(256), 0, stream>>>(weight, wbf, 524288);
  transposeQ<<<dim3(512), dim3(256), 0, stream>>>(decorr, qT);
  make_p<<<dim3(512), dim3(256), 0, stream>>>(decorr, pbf);
  gather_rows<<<dim3(8192), dim3(256), 0, stream>>>(x, sidx, self32, selbf);

  // fused = W @ Q  ->  bf16 (A=wbf 2048xK, B=qT 1024xK)
  gemm128<1><<<dim3(16, 8), dim3(256), 0, stream>>>(
      wbf, qT, 2048, 1024, 1024, nullptr, fusedbf, nullptr, nullptr,
      nullptr, nullptr, nullptr, 0);
  // y = x @ fused^T + bias
  gemm128<0><<<dim3(256, 16), dim3(256), 0, stream>>>(
      xbf, fusedbf, 32768, 2048, 1024, y, nullptr, bias, nullptr,
      nullptr, nullptr, nullptr, 0);
  // sd = sel + sel @ P^T; S2/S4 row sums; sdT transposed bf16
  gemm128<2><<<dim3(64, 8), dim3(256), 0, stream>>>(
      selbf, pbf, 8192, 1024, 1024, nullptr, nullptr, nullptr, self32,
      S2, S4, sdT, 8192);
  // grad = 0.5 * (sdT sdT^T)/N - 0.5 I
  mgemm64<<<dim3(16, 16), dim3(256), 0, stream>>>(sdT, 1024, 8192, grad,
                                                  1.0f / 8192.0f);
  loss_final<<<dim3(1), dim3(256), 0, stream>>>(S2, S4, losses);
}